// Round 4
// baseline (276.817 us; speedup 1.0000x reference)
//
#include <hip/hip_runtime.h>

#define BSZn 16
#define SEQn 2048
#define DIN 256
#define DST 1024
#define DOUTn 256
#define KXn 10
#define TCH 64
#define NCH 32

typedef __attribute__((ext_vector_type(4))) float f32x4;
typedef __attribute__((ext_vector_type(8))) short bf16x8;

__device__ __forceinline__ unsigned short f2bf(float f){
  unsigned u = __float_as_uint(f);
  u += 0x7FFF + ((u>>16)&1);
  return (unsigned short)(u>>16);
}
__device__ __forceinline__ float bf2f(unsigned short s){
  return __uint_as_float(((unsigned)s)<<16);
}

// XOR-swizzled LDS element index for [*][256] bf16 tiles (row stride 512B)
#define XIDX(r,c) ((((r)<<8) + (c)) ^ (((r)&7)<<3))

// h2 fragment-major layout: element (t,s) of batch b lives at
//   ((b*129 + (t>>4))*32 + (s>>5))*512 + (t&15)*32 + (s&31)
// (129th t-block per batch = zero tail rows 2048..2063)

// ---------------- K0: weight prep -> fragment-major bf16 ----------------
// Bt2[(d>>5)][s][d&31], Ct2[(s>>5)][o][s&31], Mt2[(k>>5)][o][k&31], k=i*256+j
__global__ void k_prep(const float* __restrict__ B, const float* __restrict__ C,
                       const float* __restrict__ M, unsigned short* __restrict__ Bt2,
                       unsigned short* __restrict__ Ct2, unsigned short* __restrict__ Mt2){
  int stride = gridDim.x*blockDim.x;
  int i0 = blockIdx.x*blockDim.x + threadIdx.x;
  for(int idx=i0; idx<DIN*DST; idx+=stride){
    int kb = idx>>15, s = (idx>>5)&1023, dl = idx&31;
    int d = (kb<<5)+dl;
    Bt2[idx] = f2bf(B[d*DST + s]);
  }
  for(int idx=i0; idx<DST*DOUTn; idx+=stride){
    int kb = idx>>13, o = (idx>>5)&255, sl = idx&31;
    int s = (kb<<5)+sl;
    Ct2[idx] = f2bf(C[s*DOUTn + o]);
  }
  for(int idx=i0; idx<DOUTn*DIN*KXn; idx+=stride){
    int kq = idx>>13, o = (idx>>5)&255, kl = idx&31;
    int k = (kq<<5)+kl, ii = k>>8, j = k&255;
    Mt2[idx] = f2bf(M[(o*DIN+j)*KXn + ii]);
  }
}

// ---- K1: uB = x@B, written DIRECTLY in h2 fragment-major layout + partials P
__global__ __launch_bounds__(256) void k_ub(const float* __restrict__ x,
    const unsigned short* __restrict__ Bt2, const float* __restrict__ A,
    unsigned short* __restrict__ uB, float* __restrict__ P){
  __shared__ __align__(16) unsigned short xt[64*256];
  int wg = blockIdx.x;
  int q = wg & 3, c = (wg>>2)&31, b = wg>>7;
  int t0 = c*TCH, s0 = q<<8;
  const float* xb = x + (size_t)b*SEQn*DIN;
  int tid = threadIdx.x;
  for(int e = tid; e < 64*64; e += 256){
    int r = e>>6, c4 = (e&63)<<2;
    float4 v = *(const float4*)(xb + (t0+r)*DIN + c4);
    ushort4 w; w.x=f2bf(v.x); w.y=f2bf(v.y); w.z=f2bf(v.z); w.w=f2bf(v.w);
    *(ushort4*)&xt[XIDX(r,c4)] = w;
  }
  __syncthreads();
  int wv = tid>>6, ln = tid&63, lm = ln&15, lk = (ln>>4)<<3, rr = (ln>>4)<<2;
  f32x4 zf = {0.f,0.f,0.f,0.f};
  f32x4 acc[4][4];
  #pragma unroll
  for(int tt=0;tt<4;tt++)
    #pragma unroll
    for(int nt=0;nt<4;nt++) acc[tt][nt] = zf;
  #pragma unroll
  for(int kb=0;kb<8;kb++){
    bf16x8 af[4];
    #pragma unroll
    for(int tt=0;tt<4;tt++)
      af[tt] = *(const bf16x8*)&xt[XIDX((tt<<4)+lm, (kb<<5)+lk)];
    #pragma unroll
    for(int nt=0;nt<4;nt++){
      int sg = s0 + (wv<<6) + (nt<<4) + lm;
      bf16x8 bfr = *(const bf16x8*)&Bt2[(kb<<15) + (sg<<5) + lk];
      #pragma unroll
      for(int tt=0;tt<4;tt++)
        acc[tt][nt] = __builtin_amdgcn_mfma_f32_16x16x32_bf16(af[tt], bfr, acc[tt][nt], 0,0,0);
    }
  }
  __syncthreads();
  #pragma unroll
  for(int tt=0;tt<4;tt++)
    #pragma unroll
    for(int nt=0;nt<4;nt++)
      #pragma unroll
      for(int r4=0;r4<4;r4++)
        xt[XIDX((tt<<4)+rr+r4, (wv<<6)+(nt<<4)+lm)] = f2bf(acc[tt][nt][r4]);
  __syncthreads();
  // write tile into h2 fragment-major layout
  unsigned short* hb = uB + ((size_t)b*129)*32*512;
  #pragma unroll
  for(int it=0; it<8; it++){
    int j = it*256 + tid;
    int r = j>>5, c0 = (j&31)<<3;
    bf16x8 v = *(const bf16x8*)&xt[XIDX(r,c0)];
    int s = s0 + c0;
    size_t addr = (((size_t)(c*4 + (r>>4)))*32 + (s>>5))*512 + ((r&15)<<5) + (s&31);
    *(bf16x8*)&hb[addr] = v;
  }
  // zero tail t-block (rows 2048..2063) for this s-quadrant
  if(c == 31){
    unsigned* zp = (unsigned*)(uB + (((size_t)b*129 + 128)*32 + (q<<3))*512);
    for(int e = tid; e < 2048; e += 256) zp[e] = 0u;
  }
  // chunk partial: P[b][c][s] = sum_t A^(63-t) uB[t]
  {
    int s = s0 + tid;
    float Av = A[s];
    float p = 0.f;
    #pragma unroll
    for(int t=0;t<64;t++)
      p = fmaf(Av, p, bf2f(xt[XIDX(t, tid)]));
    P[(((b<<5)+c)<<10) + s] = p;
  }
}

// ---------------- K2: boundary states entering each chunk ----------------
__global__ void k_bound(const float* __restrict__ A, const float* __restrict__ h0,
                        const float* __restrict__ P, float* __restrict__ bound){
  int i = blockIdx.x*blockDim.x + threadIdx.x;
  if(i >= BSZn*DST) return;
  int b = i >> 10, s = i & 1023;
  float Av = A[s];
  float a2=Av*Av, a4=a2*a2, a8=a4*a4, a16=a8*a8, a32=a16*a16, a64=a32*a32;
  const float* Pb = P + ((size_t)(b<<5)<<10);
  float* Bb = bound + ((size_t)(b<<5)<<10);
  float h = h0[s];
  Bb[s] = h;
  for(int c=1;c<NCH;c++){
    h = fmaf(a64, h, Pb[((c-1)<<10)+s]);
    Bb[(c<<10)+s] = h;
  }
}

// ---------------- K3: pure in-place scan in h2 layout ----------------
__global__ __launch_bounds__(256) void k_h(unsigned short* __restrict__ uB,
    const float* __restrict__ A, const float* __restrict__ bound){
  int wg = blockIdx.x;
  int half = wg & 1, c = (wg>>1) & 31, b = wg >> 6;
  int tid = threadIdx.x;
  int s = (half<<9) + (tid<<1);
  float Av0 = A[s], Av1 = A[s+1];
  const float* bp = bound + (((size_t)(b<<5)+c)<<10) + s;
  float h0v = bp[0], h1v = bp[1];
  unsigned short* hb = uB + (((size_t)b*129 + c*4)*32 + (s>>5))*512 + (s&31);
  #pragma unroll 4
  for(int t=0;t<64;t++){
    unsigned* p = (unsigned*)(hb + ((t>>4)*32*512) + ((t&15)<<5));
    unsigned v = *p;
    h0v = fmaf(Av0, h0v, bf2f((unsigned short)(v & 0xffff)));
    h1v = fmaf(Av1, h1v, bf2f((unsigned short)(v >> 16)));
    *p = (unsigned)f2bf(h0v) | (((unsigned)f2bf(h1v))<<16);
  }
}

// ------- K4: AR-GEMM + C-GEMM, o-half per block, h fragments from global -----
__global__ __launch_bounds__(256,4) void k_arc(const float* __restrict__ x,
    const unsigned short* __restrict__ Mt2, const unsigned short* __restrict__ Ct2,
    const unsigned short* __restrict__ h2, float* __restrict__ out){
  __shared__ __align__(16) unsigned short xt[73*256];
  int wg = blockIdx.x;
  int oh = wg & 1, c = (wg>>1)&31, b = wg>>6;
  int t0 = c*TCH;
  const float* xb = x + (size_t)b*SEQn*DIN;
  int tid = threadIdx.x;
  for(int e = tid; e < 73*64; e += 256){
    int r = e>>6, c4 = (e&63)<<2;
    int t = t0 - 9 + r;
    float4 v = {0.f,0.f,0.f,0.f};
    if(t >= 0) v = *(const float4*)(xb + t*DIN + c4);
    ushort4 w; w.x=f2bf(v.x); w.y=f2bf(v.y); w.z=f2bf(v.z); w.w=f2bf(v.w);
    *(ushort4*)&xt[XIDX(r, c4)] = w;
  }
  __syncthreads();
  int wv = tid>>6, ln = tid&63, lm = ln&15, lk = (ln>>4)<<3, rr = (ln>>4)<<2;
  int obase = (oh<<7) + (wv<<5);
  f32x4 zf = {0.f,0.f,0.f,0.f};
  f32x4 acc[4][2];
  #pragma unroll
  for(int tt=0;tt<4;tt++)
    #pragma unroll
    for(int nt=0;nt<2;nt++) acc[tt][nt] = zf;
  // ---- AR GEMM: K = 10*256 ----
  for(int i=0;i<KXn;i++){
    #pragma unroll
    for(int kb8=0;kb8<8;kb8++){
      int col = (kb8<<5) + lk;
      int kq = i*8 + kb8;
      bf16x8 af[4];
      #pragma unroll
      for(int tt=0;tt<4;tt++)
        af[tt] = *(const bf16x8*)&xt[XIDX((tt<<4)+lm + 9 - i, col)];
      #pragma unroll
      for(int nt=0;nt<2;nt++){
        int o = obase + (nt<<4) + lm;
        bf16x8 bfr = *(const bf16x8*)&Mt2[(kq<<13) + (o<<5) + lk];
        #pragma unroll
        for(int tt=0;tt<4;tt++)
          acc[tt][nt] = __builtin_amdgcn_mfma_f32_16x16x32_bf16(af[tt], bfr, acc[tt][nt], 0,0,0);
      }
    }
  }
  // ---- C GEMM: K = 1024, h rows t0+10..t0+73 direct from h2 (split base) ----
  const unsigned short* hb = h2 + (size_t)b*129*32*512;
  int Tg0 = c*4 + (lm>=6 ? 1 : 0);
  int rowin = (lm<6) ? (10+lm) : (lm-6);
  #pragma unroll
  for(int kb=0;kb<32;kb++){
    bf16x8 af[4];
    #pragma unroll
    for(int tt=0;tt<4;tt++)
      af[tt] = *(const bf16x8*)&hb[(((size_t)(Tg0+tt))*32 + kb)*512 + rowin*32 + lk];
    #pragma unroll
    for(int nt=0;nt<2;nt++){
      int o = obase + (nt<<4) + lm;
      bf16x8 bfr = *(const bf16x8*)&Ct2[(kb<<13) + (o<<5) + lk];
      #pragma unroll
      for(int tt=0;tt<4;tt++)
        acc[tt][nt] = __builtin_amdgcn_mfma_f32_16x16x32_bf16(af[tt], bfr, acc[tt][nt], 0,0,0);
    }
  }
  #pragma unroll
  for(int tt=0;tt<4;tt++)
    #pragma unroll
    for(int nt=0;nt<2;nt++)
      #pragma unroll
      for(int r4=0;r4<4;r4++){
        int m = (tt<<4) + rr + r4;
        int o = obase + (nt<<4) + lm;
        out[((size_t)b*SEQn + t0 + m)*DOUTn + o] = acc[tt][nt][r4];
      }
}

extern "C" void kernel_launch(void* const* d_in, const int* in_sizes, int n_in,
                              void* d_out, int out_size, void* d_ws, size_t ws_size,
                              hipStream_t stream){
  const float* x  = (const float*)d_in[0];
  const float* h0 = (const float*)d_in[1];
  const float* A  = (const float*)d_in[2];
  const float* B  = (const float*)d_in[3];
  const float* C  = (const float*)d_in[4];
  const float* M  = (const float*)d_in[5];
  float* out = (float*)d_out;
  unsigned short* Bt2 = (unsigned short*)d_ws;                   // 512 KB
  unsigned short* Ct2 = Bt2 + DIN*DST;                           // 512 KB
  unsigned short* Mt2 = Ct2 + DST*DOUTn;                         // 1.31 MB
  float* P     = (float*)((char*)d_ws + ( 4u<<20));              // 2 MB
  float* bound = (float*)((char*)d_ws + ( 6u<<20));              // 2 MB
  unsigned short* uB = (unsigned short*)((char*)d_ws + (8u<<20)); // 67.6 MB (uB/h2)
  k_prep <<<512, 256, 0, stream>>>(B, C, M, Bt2, Ct2, Mt2);
  k_ub   <<<BSZn*NCH*4, 256, 0, stream>>>(x, Bt2, A, uB, P);
  k_bound<<<(BSZn*DST)/256, 256, 0, stream>>>(A, h0, P, bound);
  k_h    <<<BSZn*NCH*2, 256, 0, stream>>>(uB, A, bound);
  k_arc  <<<BSZn*NCH*2, 256, 0, stream>>>(x, Mt2, Ct2, uB, out);
}

// Round 6
// 255.777 us; speedup vs baseline: 1.0823x; 1.0823x over previous
//
#include <hip/hip_runtime.h>

#define BSZn 16
#define SEQn 2048
#define DIN 256
#define DST 1024
#define DOUTn 256
#define KXn 10
#define TCH 64
#define NCH 32

typedef __attribute__((ext_vector_type(4))) float f32x4;
typedef __attribute__((ext_vector_type(8))) short bf16x8;

__device__ __forceinline__ unsigned short f2bf(float f){
  unsigned u = __float_as_uint(f);
  u += 0x7FFF + ((u>>16)&1);
  return (unsigned short)(u>>16);
}
__device__ __forceinline__ float bf2f(unsigned short s){
  return __uint_as_float(((unsigned)s)<<16);
}

// XOR-swizzled LDS element index for [*][256] bf16 tiles (row stride 512B)
#define XIDX(r,c) ((((r)<<8) + (c)) ^ (((r)&7)<<3))

// h2 fragment-major layout: element (t,s) of batch b lives at
//   ((b*129 + (t>>4))*32 + (s>>5))*512 + (t&15)*32 + (s&31)
// (129th t-block per batch = zero tail rows 2048..2063)

// ------ K0: weight prep -> fragment-major bf16 (coalesced reads, scattered writes)
// Bt2[(d>>5)][s][d&31], Ct2[(s>>5)][o][s&31], Mt2[(k>>5)][o][k&31], k=i*256+j
__global__ void k_prep(const float* __restrict__ B, const float* __restrict__ C,
                       const float* __restrict__ M, unsigned short* __restrict__ Bt2,
                       unsigned short* __restrict__ Ct2, unsigned short* __restrict__ Mt2){
  int stride = gridDim.x*blockDim.x;
  int i0 = blockIdx.x*blockDim.x + threadIdx.x;
  for(int idx=i0; idx<DIN*DST; idx+=stride){         // src-contiguous over B[d][s]
    int d = idx>>10, s = idx&1023;
    Bt2[((d>>5)<<15) + (s<<5) + (d&31)] = f2bf(B[idx]);
  }
  for(int idx=i0; idx<DST*DOUTn; idx+=stride){       // src-contiguous over C[s][o]
    int s = idx>>8, o = idx&255;
    Ct2[((s>>5)<<13) + (o<<5) + (s&31)] = f2bf(C[idx]);
  }
  for(int idx=i0; idx<DOUTn*DIN*KXn; idx+=stride){   // src-contiguous over M[o][j][i]
    int q = idx/KXn, ii = idx - q*KXn;
    int o = q>>8, j = q&255;
    int k = (ii<<8) + j;
    Mt2[((k>>5)<<13) + (o<<5) + (k&31)] = f2bf(M[idx]);
  }
}

// ---- K1: uB = x@B, written DIRECTLY in h2 fragment-major layout + partials P
__global__ __launch_bounds__(256) void k_ub(const float* __restrict__ x,
    const unsigned short* __restrict__ Bt2, const float* __restrict__ A,
    unsigned short* __restrict__ uB, float* __restrict__ P){
  __shared__ __align__(16) unsigned short xt[64*256];
  int wg = blockIdx.x;
  int q = wg & 3, c = (wg>>2)&31, b = wg>>7;
  int t0 = c*TCH, s0 = q<<8;
  const float* xb = x + (size_t)b*SEQn*DIN;
  int tid = threadIdx.x;
  for(int e = tid; e < 64*64; e += 256){
    int r = e>>6, c4 = (e&63)<<2;
    float4 v = *(const float4*)(xb + (t0+r)*DIN + c4);
    ushort4 w; w.x=f2bf(v.x); w.y=f2bf(v.y); w.z=f2bf(v.z); w.w=f2bf(v.w);
    *(ushort4*)&xt[XIDX(r,c4)] = w;
  }
  __syncthreads();
  int wv = tid>>6, ln = tid&63, lm = ln&15, lk = (ln>>4)<<3, rr = (ln>>4)<<2;
  f32x4 zf = {0.f,0.f,0.f,0.f};
  f32x4 acc[4][4];
  #pragma unroll
  for(int tt=0;tt<4;tt++)
    #pragma unroll
    for(int nt=0;nt<4;nt++) acc[tt][nt] = zf;
  #pragma unroll
  for(int kb=0;kb<8;kb++){
    bf16x8 af[4];
    #pragma unroll
    for(int tt=0;tt<4;tt++)
      af[tt] = *(const bf16x8*)&xt[XIDX((tt<<4)+lm, (kb<<5)+lk)];
    #pragma unroll
    for(int nt=0;nt<4;nt++){
      int sg = s0 + (wv<<6) + (nt<<4) + lm;
      bf16x8 bfr = *(const bf16x8*)&Bt2[(kb<<15) + (sg<<5) + lk];
      #pragma unroll
      for(int tt=0;tt<4;tt++)
        acc[tt][nt] = __builtin_amdgcn_mfma_f32_16x16x32_bf16(af[tt], bfr, acc[tt][nt], 0,0,0);
    }
  }
  __syncthreads();
  #pragma unroll
  for(int tt=0;tt<4;tt++)
    #pragma unroll
    for(int nt=0;nt<4;nt++)
      #pragma unroll
      for(int r4=0;r4<4;r4++)
        xt[XIDX((tt<<4)+rr+r4, (wv<<6)+(nt<<4)+lm)] = f2bf(acc[tt][nt][r4]);
  __syncthreads();
  // write tile into h2 fragment-major layout
  unsigned short* hb = uB + ((size_t)b*129)*32*512;
  #pragma unroll
  for(int it=0; it<8; it++){
    int j = it*256 + tid;
    int r = j>>5, c0 = (j&31)<<3;
    bf16x8 v = *(const bf16x8*)&xt[XIDX(r,c0)];
    int s = s0 + c0;
    size_t addr = (((size_t)(c*4 + (r>>4)))*32 + (s>>5))*512 + ((r&15)<<5) + (s&31);
    *(bf16x8*)&hb[addr] = v;
  }
  // zero tail t-block (rows 2048..2063) for this s-quadrant
  if(c == 31){
    unsigned* zp = (unsigned*)(uB + (((size_t)b*129 + 128)*32 + (q<<3))*512);
    for(int e = tid; e < 2048; e += 256) zp[e] = 0u;
  }
  // chunk partial: P[b][c][s] = sum_t A^(63-t) uB[t]
  {
    int s = s0 + tid;
    float Av = A[s];
    float p = 0.f;
    #pragma unroll
    for(int t=0;t<64;t++)
      p = fmaf(Av, p, bf2f(xt[XIDX(t, tid)]));
    P[(((b<<5)+c)<<10) + s] = p;
  }
}

// ---- K3: boundary combine (inline) + pure in-place scan in h2 layout ----
__global__ __launch_bounds__(256) void k_h(unsigned short* __restrict__ uB,
    const float* __restrict__ A, const float* __restrict__ h0,
    const float* __restrict__ P){
  int wg = blockIdx.x;
  int half = wg & 1, c = (wg>>1) & 31, b = wg >> 6;
  int tid = threadIdx.x;
  int s = (half<<9) + (tid<<1);
  float2 Av = *(const float2*)(A + s);
  // a64 = A^64
  float a0 = Av.x, a1 = Av.y;
  #pragma unroll
  for(int sq=0;sq<6;sq++){ a0 *= a0; a1 *= a1; }
  // boundary state entering chunk c: h = h0; for j<c: h = a64*h + P[j]
  float2 hv = *(const float2*)(h0 + s);
  float h0v = hv.x, h1v = hv.y;
  const float2* Pb = (const float2*)(P + (((size_t)(b<<5))<<10) + s);
  for(int j=0;j<c;j++){
    float2 pv = Pb[(size_t)j<<9];
    h0v = fmaf(a0, h0v, pv.x);
    h1v = fmaf(a1, h1v, pv.y);
  }
  // in-place scan over this chunk's 64 rows in h2 layout
  unsigned short* hb = uB + (((size_t)b*129 + c*4)*32 + (s>>5))*512 + (s&31);
  #pragma unroll 4
  for(int t=0;t<64;t++){
    unsigned* p = (unsigned*)(hb + ((t>>4)*32*512) + ((t&15)<<5));
    unsigned v = *p;
    h0v = fmaf(Av.x, h0v, bf2f((unsigned short)(v & 0xffff)));
    h1v = fmaf(Av.y, h1v, bf2f((unsigned short)(v >> 16)));
    *p = (unsigned)f2bf(h0v) | (((unsigned)f2bf(h1v))<<16);
  }
}

// ------- K4: AR-GEMM + C-GEMM, full o per block, deep register pipelining ----
__global__ __launch_bounds__(256,2) void k_arc(const float* __restrict__ x,
    const unsigned short* __restrict__ Mt2, const unsigned short* __restrict__ Ct2,
    const unsigned short* __restrict__ h2, float* __restrict__ out){
  __shared__ __align__(16) unsigned short xt[73*256];
  int wg = blockIdx.x;
  int b = wg>>5, c = wg&31;
  int t0 = c*TCH;
  const float* xb = x + (size_t)b*SEQn*DIN;
  int tid = threadIdx.x;
  for(int e = tid; e < 73*64; e += 256){
    int r = e>>6, c4 = (e&63)<<2;
    int t = t0 - 9 + r;
    float4 v = {0.f,0.f,0.f,0.f};
    if(t >= 0) v = *(const float4*)(xb + t*DIN + c4);
    ushort4 w; w.x=f2bf(v.x); w.y=f2bf(v.y); w.z=f2bf(v.z); w.w=f2bf(v.w);
    *(ushort4*)&xt[XIDX(r, c4)] = w;
  }
  __syncthreads();
  int wv = tid>>6, ln = tid&63, lm = ln&15, lk = (ln>>4)<<3, rr = (ln>>4)<<2;
  f32x4 zf = {0.f,0.f,0.f,0.f};
  f32x4 acc[4][4];
  #pragma unroll
  for(int tt=0;tt<4;tt++)
    #pragma unroll
    for(int nt=0;nt<4;nt++) acc[tt][nt] = zf;
  // ---- AR GEMM: K = 10*256 ----
  #pragma unroll 2
  for(int i=0;i<KXn;i++){
    #pragma unroll
    for(int kb8=0;kb8<8;kb8++){
      int col = (kb8<<5) + lk;
      int kq = i*8 + kb8;
      bf16x8 af[4];
      #pragma unroll
      for(int tt=0;tt<4;tt++)
        af[tt] = *(const bf16x8*)&xt[XIDX((tt<<4)+lm + 9 - i, col)];
      #pragma unroll
      for(int nt=0;nt<4;nt++){
        int o = (wv<<6) + (nt<<4) + lm;
        bf16x8 bfr = *(const bf16x8*)&Mt2[(kq<<13) + (o<<5) + lk];
        #pragma unroll
        for(int tt=0;tt<4;tt++)
          acc[tt][nt] = __builtin_amdgcn_mfma_f32_16x16x32_bf16(af[tt], bfr, acc[tt][nt], 0,0,0);
      }
    }
  }
  // ---- C GEMM: K = 1024, h rows t0+10..t0+73 direct from h2 (split base) ----
  const unsigned short* hb = h2 + (size_t)b*129*32*512;
  int Tg0 = c*4 + (lm>=6 ? 1 : 0);
  int rowin = (lm<6) ? (10+lm) : (lm-6);
  #pragma unroll
  for(int kb=0;kb<32;kb++){
    bf16x8 af[4];
    #pragma unroll
    for(int tt=0;tt<4;tt++)
      af[tt] = *(const bf16x8*)&hb[(((size_t)(Tg0+tt))*32 + kb)*512 + rowin*32 + lk];
    #pragma unroll
    for(int nt=0;nt<4;nt++){
      int o = (wv<<6) + (nt<<4) + lm;
      bf16x8 bfr = *(const bf16x8*)&Ct2[(kb<<13) + (o<<5) + lk];
      #pragma unroll
      for(int tt=0;tt<4;tt++)
        acc[tt][nt] = __builtin_amdgcn_mfma_f32_16x16x32_bf16(af[tt], bfr, acc[tt][nt], 0,0,0);
    }
  }
  #pragma unroll
  for(int tt=0;tt<4;tt++)
    #pragma unroll
    for(int nt=0;nt<4;nt++)
      #pragma unroll
      for(int r4=0;r4<4;r4++){
        int m = (tt<<4) + rr + r4;
        int o = (wv<<6) + (nt<<4) + lm;
        out[((size_t)b*SEQn + t0 + m)*DOUTn + o] = acc[tt][nt][r4];
      }
}

extern "C" void kernel_launch(void* const* d_in, const int* in_sizes, int n_in,
                              void* d_out, int out_size, void* d_ws, size_t ws_size,
                              hipStream_t stream){
  const float* x  = (const float*)d_in[0];
  const float* h0 = (const float*)d_in[1];
  const float* A  = (const float*)d_in[2];
  const float* B  = (const float*)d_in[3];
  const float* C  = (const float*)d_in[4];
  const float* M  = (const float*)d_in[5];
  float* out = (float*)d_out;
  unsigned short* Bt2 = (unsigned short*)d_ws;                   // 512 KB
  unsigned short* Ct2 = Bt2 + DIN*DST;                           // 512 KB
  unsigned short* Mt2 = Ct2 + DST*DOUTn;                         // 1.31 MB
  float* P     = (float*)((char*)d_ws + ( 4u<<20));              // 2 MB
  unsigned short* uB = (unsigned short*)((char*)d_ws + (8u<<20)); // 67.6 MB (uB/h2)
  k_prep <<<512, 256, 0, stream>>>(B, C, M, Bt2, Ct2, Mt2);
  k_ub   <<<BSZn*NCH*4, 256, 0, stream>>>(x, Bt2, A, uB, P);
  k_h    <<<BSZn*NCH*2, 256, 0, stream>>>(uB, A, h0, P);
  k_arc  <<<BSZn*NCH, 256, 0, stream>>>(x, Mt2, Ct2, uB, out);
}

// Round 7
// 252.235 us; speedup vs baseline: 1.0975x; 1.0140x over previous
//
#include <hip/hip_runtime.h>

#define BSZn 16
#define SEQn 2048
#define DIN 256
#define DST 1024
#define DOUTn 256
#define KXn 10
#define TCH 64
#define NCH 32

typedef __attribute__((ext_vector_type(4))) float f32x4;
typedef __attribute__((ext_vector_type(8))) short bf16x8;

__device__ __forceinline__ unsigned short f2bf(float f){
  unsigned u = __float_as_uint(f);
  u += 0x7FFF + ((u>>16)&1);
  return (unsigned short)(u>>16);
}
__device__ __forceinline__ float bf2f(unsigned short s){
  return __uint_as_float(((unsigned)s)<<16);
}

// XOR-swizzled LDS element index for [*][256] bf16 tiles (row stride 512B)
#define XIDX(r,c) ((((r)<<8) + (c)) ^ (((r)&7)<<3))

// h2 fragment-major layout: element (t,s) of batch b lives at
//   ((b*129 + (t>>4))*32 + (s>>5))*512 + (t&15)*32 + (s&31)
// (129th t-block per batch = zero tail rows 2048..2063)

// ------ K0: weight prep -> fragment-major bf16 (coalesced reads, scattered writes)
// Bt2[(d>>5)][s][d&31], Ct2[(s>>5)][o][s&31], Mt2[(k>>5)][o][k&31], k=i*256+j
__global__ void k_prep(const float* __restrict__ B, const float* __restrict__ C,
                       const float* __restrict__ M, unsigned short* __restrict__ Bt2,
                       unsigned short* __restrict__ Ct2, unsigned short* __restrict__ Mt2){
  int stride = gridDim.x*blockDim.x;
  int i0 = blockIdx.x*blockDim.x + threadIdx.x;
  for(int idx=i0; idx<DIN*DST; idx+=stride){         // src-contiguous over B[d][s]
    int d = idx>>10, s = idx&1023;
    Bt2[((d>>5)<<15) + (s<<5) + (d&31)] = f2bf(B[idx]);
  }
  for(int idx=i0; idx<DST*DOUTn; idx+=stride){       // src-contiguous over C[s][o]
    int s = idx>>8, o = idx&255;
    Ct2[((s>>5)<<13) + (o<<5) + (s&31)] = f2bf(C[idx]);
  }
  for(int idx=i0; idx<DOUTn*DIN*KXn; idx+=stride){   // src-contiguous over M[o][j][i]
    int q = idx/KXn, ii = idx - q*KXn;
    int o = q>>8, j = q&255;
    int k = (ii<<8) + j;
    Mt2[((k>>5)<<13) + (o<<5) + (k&31)] = f2bf(M[idx]);
  }
}

// ---- K1: uB = x@B, all 4 s-quadrants per block (x staged ONCE), h2-layout out
__global__ __launch_bounds__(256) void k_ub(const float* __restrict__ x,
    const unsigned short* __restrict__ Bt2, const float* __restrict__ A,
    unsigned short* __restrict__ uB, float* __restrict__ P){
  __shared__ __align__(16) unsigned short xt[64*256];   // x tile
  __shared__ __align__(16) unsigned short ub[64*256];   // uB tile staging
  int wg = blockIdx.x;
  int c = wg & 31, b = wg >> 5;
  int t0 = c*TCH;
  const float* xb = x + (size_t)b*SEQn*DIN;
  int tid = threadIdx.x;
  for(int e = tid; e < 64*64; e += 256){
    int r = e>>6, c4 = (e&63)<<2;
    float4 v = *(const float4*)(xb + (t0+r)*DIN + c4);
    ushort4 w; w.x=f2bf(v.x); w.y=f2bf(v.y); w.z=f2bf(v.z); w.w=f2bf(v.w);
    *(ushort4*)&xt[XIDX(r,c4)] = w;
  }
  __syncthreads();
  int wv = tid>>6, ln = tid&63, lm = ln&15, lk = (ln>>4)<<3, rr = (ln>>4)<<2;
  unsigned short* hb = uB + ((size_t)b*129)*32*512;
  f32x4 zf = {0.f,0.f,0.f,0.f};
  for(int q=0;q<4;q++){
    int s0 = q<<8;
    f32x4 acc[4][4];
    #pragma unroll
    for(int tt=0;tt<4;tt++)
      #pragma unroll
      for(int nt=0;nt<4;nt++) acc[tt][nt] = zf;
    #pragma unroll
    for(int kb=0;kb<8;kb++){
      bf16x8 af[4];
      #pragma unroll
      for(int tt=0;tt<4;tt++)
        af[tt] = *(const bf16x8*)&xt[XIDX((tt<<4)+lm, (kb<<5)+lk)];
      #pragma unroll
      for(int nt=0;nt<4;nt++){
        int sg = s0 + (wv<<6) + (nt<<4) + lm;
        bf16x8 bfr = *(const bf16x8*)&Bt2[(kb<<15) + (sg<<5) + lk];
        #pragma unroll
        for(int tt=0;tt<4;tt++)
          acc[tt][nt] = __builtin_amdgcn_mfma_f32_16x16x32_bf16(af[tt], bfr, acc[tt][nt], 0,0,0);
      }
    }
    __syncthreads();   // previous q's readers of ub are done
    #pragma unroll
    for(int tt=0;tt<4;tt++)
      #pragma unroll
      for(int nt=0;nt<4;nt++)
        #pragma unroll
        for(int r4=0;r4<4;r4++)
          ub[XIDX((tt<<4)+rr+r4, (wv<<6)+(nt<<4)+lm)] = f2bf(acc[tt][nt][r4]);
    __syncthreads();
    // coalesced write into h2 fragment-major layout
    #pragma unroll
    for(int it=0; it<8; it++){
      int j = it*256 + tid;
      int r = j>>5, c0 = (j&31)<<3;
      bf16x8 v = *(const bf16x8*)&ub[XIDX(r,c0)];
      int s = s0 + c0;
      size_t addr = (((size_t)(c*4 + (r>>4)))*32 + (s>>5))*512 + ((r&15)<<5) + (s&31);
      *(bf16x8*)&hb[addr] = v;
    }
    // chunk partial for this quadrant
    {
      int s = s0 + tid;
      float Av = A[s];
      float p = 0.f;
      #pragma unroll
      for(int t=0;t<64;t++)
        p = fmaf(Av, p, bf2f(ub[XIDX(t, tid)]));
      P[(((b<<5)+c)<<10) + s] = p;
    }
  }
  // zero tail t-block (rows 2048..2063)
  if(c == 31){
    unsigned* zp = (unsigned*)(uB + (((size_t)b*129 + 128)*32)*512);
    for(int e = tid; e < 8192; e += 256) zp[e] = 0u;
  }
}

// ---- K3: boundary combine (inline) + pure in-place scan in h2 layout ----
__global__ __launch_bounds__(256) void k_h(unsigned short* __restrict__ uB,
    const float* __restrict__ A, const float* __restrict__ h0,
    const float* __restrict__ P){
  int wg = blockIdx.x;
  int half = wg & 1, c = (wg>>1) & 31, b = wg >> 6;
  int tid = threadIdx.x;
  int s = (half<<9) + (tid<<1);
  float2 Av = *(const float2*)(A + s);
  float a0 = Av.x, a1 = Av.y;
  #pragma unroll
  for(int sq=0;sq<6;sq++){ a0 *= a0; a1 *= a1; }   // A^64
  float2 hv = *(const float2*)(h0 + s);
  float h0v = hv.x, h1v = hv.y;
  const float2* Pb = (const float2*)(P + (((size_t)(b<<5))<<10) + s);
  for(int j=0;j<c;j++){
    float2 pv = Pb[(size_t)j<<9];
    h0v = fmaf(a0, h0v, pv.x);
    h1v = fmaf(a1, h1v, pv.y);
  }
  unsigned short* hb = uB + (((size_t)b*129 + c*4)*32 + (s>>5))*512 + (s&31);
  #pragma unroll 4
  for(int t=0;t<64;t++){
    unsigned* p = (unsigned*)(hb + ((t>>4)*32*512) + ((t&15)<<5));
    unsigned v = *p;
    h0v = fmaf(Av.x, h0v, bf2f((unsigned short)(v & 0xffff)));
    h1v = fmaf(Av.y, h1v, bf2f((unsigned short)(v >> 16)));
    *p = (unsigned)f2bf(h0v) | (((unsigned)f2bf(h1v))<<16);
  }
}

// ------- K4: AR-GEMM + C-GEMM, explicit 2-deep register prefetch pipeline ----
__global__ __launch_bounds__(256,2) void k_arc(const float* __restrict__ x,
    const unsigned short* __restrict__ Mt2, const unsigned short* __restrict__ Ct2,
    const unsigned short* __restrict__ h2, float* __restrict__ out){
  __shared__ __align__(16) unsigned short xt[73*256];
  int wg = blockIdx.x;
  int b = wg>>5, c = wg&31;
  int t0 = c*TCH;
  const float* xb = x + (size_t)b*SEQn*DIN;
  int tid = threadIdx.x;
  for(int e = tid; e < 73*64; e += 256){
    int r = e>>6, c4 = (e&63)<<2;
    int t = t0 - 9 + r;
    float4 v = {0.f,0.f,0.f,0.f};
    if(t >= 0) v = *(const float4*)(xb + t*DIN + c4);
    ushort4 w; w.x=f2bf(v.x); w.y=f2bf(v.y); w.z=f2bf(v.z); w.w=f2bf(v.w);
    *(ushort4*)&xt[XIDX(r, c4)] = w;
  }
  __syncthreads();
  int wv = tid>>6, ln = tid&63, lm = ln&15, lk = (ln>>4)<<3, rr = (ln>>4)<<2;
  f32x4 zf = {0.f,0.f,0.f,0.f};
  f32x4 acc[4][4];
  #pragma unroll
  for(int tt=0;tt<4;tt++)
    #pragma unroll
    for(int nt=0;nt<4;nt++) acc[tt][nt] = zf;

  // ---- AR GEMM: 80 K-iterations (it = i*8+kb8), groups of 2, ping-pong ----
  const unsigned short* mb = Mt2 + ((((wv<<6)+lm)<<5) + lk);
  bf16x8 pA[8], pB[8];
#define LOADG(buf, IT0) { _Pragma("unroll") \
    for(int j=0;j<8;j++){ int itt=(IT0)+(j>>2); \
      buf[j] = *(const bf16x8*)&mb[((size_t)itt<<13) + ((j&3)<<9)]; } }
#define COMPG(buf, IT0) { _Pragma("unroll") \
    for(int jj=0;jj<2;jj++){ int itc=(IT0)+jj; int ii=itc>>3, k8=itc&7; \
      int col=(k8<<5)+lk; bf16x8 af[4]; \
      _Pragma("unroll") for(int tt=0;tt<4;tt++) \
        af[tt] = *(const bf16x8*)&xt[XIDX((tt<<4)+lm+9-ii, col)]; \
      _Pragma("unroll") for(int nt=0;nt<4;nt++){ \
        _Pragma("unroll") for(int tt=0;tt<4;tt++) \
          acc[tt][nt] = __builtin_amdgcn_mfma_f32_16x16x32_bf16(af[tt], buf[jj*4+nt], acc[tt][nt],0,0,0); } } }
  LOADG(pA, 0)
  for(int g=0; g<80; g+=4){
    LOADG(pB, g+2)
    COMPG(pA, g)
    if(g+4 < 80) LOADG(pA, g+4)
    COMPG(pB, g+2)
  }

  // ---- C GEMM: 32 K-iterations, prefetch h2(af) + Ct2(bfr) one kb ahead ----
  const unsigned short* hb = h2 + (size_t)b*129*32*512;
  int Tg0 = c*4 + (lm>=6 ? 1 : 0);
  int rowin = (lm<6) ? (10+lm) : (lm-6);
  const unsigned short* hp[4];
  #pragma unroll
  for(int tt=0;tt<4;tt++)
    hp[tt] = hb + (((size_t)(Tg0+tt)*32)<<9) + rowin*32 + lk;
  const unsigned short* cb = Ct2 + ((((wv<<6)+lm)<<5) + lk);
  bf16x8 qa[4], qb4[4], qaf[4], qbf[4];
#define CLOADG(bufA, bufB, KB) { _Pragma("unroll") \
    for(int tt=0;tt<4;tt++) bufA[tt] = *(const bf16x8*)&hp[tt][((size_t)(KB))<<9]; \
    _Pragma("unroll") \
    for(int nt=0;nt<4;nt++) bufB[nt] = *(const bf16x8*)&cb[(((size_t)(KB))<<13) + (nt<<9)]; }
#define CCOMP(bufA, bufB) { _Pragma("unroll") \
    for(int nt=0;nt<4;nt++) \
      _Pragma("unroll") for(int tt=0;tt<4;tt++) \
        acc[tt][nt] = __builtin_amdgcn_mfma_f32_16x16x32_bf16(bufA[tt], bufB[nt], acc[tt][nt],0,0,0); }
  CLOADG(qaf, qbf, 0)
  for(int kb=0; kb<32; kb+=2){
    CLOADG(qa, qb4, kb+1)
    CCOMP(qaf, qbf)
    if(kb+2 < 32) CLOADG(qaf, qbf, kb+2)
    CCOMP(qa, qb4)
  }

  #pragma unroll
  for(int tt=0;tt<4;tt++)
    #pragma unroll
    for(int nt=0;nt<4;nt++)
      #pragma unroll
      for(int r4=0;r4<4;r4++){
        int m = (tt<<4) + rr + r4;
        int o = (wv<<6) + (nt<<4) + lm;
        out[((size_t)b*SEQn + t0 + m)*DOUTn + o] = acc[tt][nt][r4];
      }
}

extern "C" void kernel_launch(void* const* d_in, const int* in_sizes, int n_in,
                              void* d_out, int out_size, void* d_ws, size_t ws_size,
                              hipStream_t stream){
  const float* x  = (const float*)d_in[0];
  const float* h0 = (const float*)d_in[1];
  const float* A  = (const float*)d_in[2];
  const float* B  = (const float*)d_in[3];
  const float* C  = (const float*)d_in[4];
  const float* M  = (const float*)d_in[5];
  float* out = (float*)d_out;
  unsigned short* Bt2 = (unsigned short*)d_ws;                   // 512 KB
  unsigned short* Ct2 = Bt2 + DIN*DST;                           // 512 KB
  unsigned short* Mt2 = Ct2 + DST*DOUTn;                         // 1.31 MB
  float* P     = (float*)((char*)d_ws + ( 4u<<20));              // 2 MB
  unsigned short* uB = (unsigned short*)((char*)d_ws + (8u<<20)); // 67.6 MB (uB/h2)
  k_prep <<<512, 256, 0, stream>>>(B, C, M, Bt2, Ct2, Mt2);
  k_ub   <<<BSZn*NCH, 256, 0, stream>>>(x, Bt2, A, uB, P);
  k_h    <<<BSZn*NCH*2, 256, 0, stream>>>(uB, A, h0, P);
  k_arc  <<<BSZn*NCH, 256, 0, stream>>>(x, Mt2, Ct2, uB, out);
}

// Round 8
// 251.964 us; speedup vs baseline: 1.0986x; 1.0011x over previous
//
#include <hip/hip_runtime.h>

#define BSZn 16
#define SEQn 2048
#define DIN 256
#define DST 1024
#define DOUTn 256
#define KXn 10
#define TCH 64
#define NCH 32

typedef __attribute__((ext_vector_type(4))) float f32x4;
typedef __attribute__((ext_vector_type(8))) short bf16x8;

#define SB __builtin_amdgcn_sched_barrier(0)

__device__ __forceinline__ unsigned short f2bf(float f){
  unsigned u = __float_as_uint(f);
  u += 0x7FFF + ((u>>16)&1);
  return (unsigned short)(u>>16);
}
__device__ __forceinline__ float bf2f(unsigned short s){
  return __uint_as_float(((unsigned)s)<<16);
}

// XOR-swizzled LDS element index for [*][256] bf16 tiles (row stride 512B)
#define XIDX(r,c) ((((r)<<8) + (c)) ^ (((r)&7)<<3))

// h2 fragment-major layout: element (t,s) of batch b lives at
//   ((b*129 + (t>>4))*32 + (s>>5))*512 + (t&15)*32 + (s&31)
// (129th t-block per batch = zero tail rows 2048..2063)

// ------ K0: weight prep -> fragment-major bf16 (coalesced reads, scattered writes)
// Bt2[(d>>5)][s][d&31], Ct2[(s>>5)][o][s&31], Mt2[(k>>5)][o][k&31], k=i*256+j
__global__ void k_prep(const float* __restrict__ B, const float* __restrict__ C,
                       const float* __restrict__ M, unsigned short* __restrict__ Bt2,
                       unsigned short* __restrict__ Ct2, unsigned short* __restrict__ Mt2){
  int stride = gridDim.x*blockDim.x;
  int i0 = blockIdx.x*blockDim.x + threadIdx.x;
  for(int idx=i0; idx<DIN*DST; idx+=stride){         // src-contiguous over B[d][s]
    int d = idx>>10, s = idx&1023;
    Bt2[((d>>5)<<15) + (s<<5) + (d&31)] = f2bf(B[idx]);
  }
  for(int idx=i0; idx<DST*DOUTn; idx+=stride){       // src-contiguous over C[s][o]
    int s = idx>>8, o = idx&255;
    Ct2[((s>>5)<<13) + (o<<5) + (s&31)] = f2bf(C[idx]);
  }
  for(int idx=i0; idx<DOUTn*DIN*KXn; idx+=stride){   // src-contiguous over M[o][j][i]
    int q = idx/KXn, ii = idx - q*KXn;
    int o = q>>8, j = q&255;
    int k = (ii<<8) + j;
    Mt2[((k>>5)<<13) + (o<<5) + (k&31)] = f2bf(M[idx]);
  }
}

// ---- K1: uB = x@B, all 4 s-quadrants per block (x staged ONCE), h2-layout out
__global__ __launch_bounds__(256) void k_ub(const float* __restrict__ x,
    const unsigned short* __restrict__ Bt2, const float* __restrict__ A,
    unsigned short* __restrict__ uB, float* __restrict__ P){
  __shared__ __align__(16) unsigned short xt[64*256];   // x tile
  __shared__ __align__(16) unsigned short ub[64*256];   // uB tile staging
  int wg = blockIdx.x;
  int c = wg & 31, b = wg >> 5;
  int t0 = c*TCH;
  const float* xb = x + (size_t)b*SEQn*DIN;
  int tid = threadIdx.x;
  for(int e = tid; e < 64*64; e += 256){
    int r = e>>6, c4 = (e&63)<<2;
    float4 v = *(const float4*)(xb + (t0+r)*DIN + c4);
    ushort4 w; w.x=f2bf(v.x); w.y=f2bf(v.y); w.z=f2bf(v.z); w.w=f2bf(v.w);
    *(ushort4*)&xt[XIDX(r,c4)] = w;
  }
  __syncthreads();
  int wv = tid>>6, ln = tid&63, lm = ln&15, lk = (ln>>4)<<3, rr = (ln>>4)<<2;
  unsigned short* hb = uB + ((size_t)b*129)*32*512;
  f32x4 zf = {0.f,0.f,0.f,0.f};
  for(int q=0;q<4;q++){
    int s0 = q<<8;
    f32x4 acc[4][4];
    #pragma unroll
    for(int tt=0;tt<4;tt++)
      #pragma unroll
      for(int nt=0;nt<4;nt++) acc[tt][nt] = zf;
    bf16x8 wA[4], wB[4];
#define UBLOAD(buf, KB) { _Pragma("unroll") for(int nt=0;nt<4;nt++){ \
      int sg = s0 + (wv<<6) + (nt<<4) + lm; \
      buf[nt] = *(const bf16x8*)&Bt2[((KB)<<15) + (sg<<5) + lk]; } }
#define UBCOMP(buf, KB) { bf16x8 af[4]; _Pragma("unroll") \
      for(int tt=0;tt<4;tt++) af[tt] = *(const bf16x8*)&xt[XIDX((tt<<4)+lm, ((KB)<<5)+lk)]; \
      _Pragma("unroll") for(int nt=0;nt<4;nt++) \
        _Pragma("unroll") for(int tt=0;tt<4;tt++) \
          acc[tt][nt] = __builtin_amdgcn_mfma_f32_16x16x32_bf16(af[tt], buf[nt], acc[tt][nt], 0,0,0); }
    UBLOAD(wA, 0) SB;
    #pragma unroll
    for(int kb=0;kb<8;kb+=2){
      UBLOAD(wB, kb+1) SB;
      UBCOMP(wA, kb) SB;
      if(kb+2<8) UBLOAD(wA, kb+2)
      SB;
      UBCOMP(wB, kb+1) SB;
    }
    __syncthreads();   // previous q's readers of ub are done
    #pragma unroll
    for(int tt=0;tt<4;tt++)
      #pragma unroll
      for(int nt=0;nt<4;nt++)
        #pragma unroll
        for(int r4=0;r4<4;r4++)
          ub[XIDX((tt<<4)+rr+r4, (wv<<6)+(nt<<4)+lm)] = f2bf(acc[tt][nt][r4]);
    __syncthreads();
    // coalesced write into h2 fragment-major layout
    #pragma unroll
    for(int it=0; it<8; it++){
      int j = it*256 + tid;
      int r = j>>5, c0 = (j&31)<<3;
      bf16x8 v = *(const bf16x8*)&ub[XIDX(r,c0)];
      int s = s0 + c0;
      size_t addr = (((size_t)(c*4 + (r>>4)))*32 + (s>>5))*512 + ((r&15)<<5) + (s&31);
      *(bf16x8*)&hb[addr] = v;
    }
    // chunk partial for this quadrant
    {
      int s = s0 + tid;
      float Av = A[s];
      float p = 0.f;
      #pragma unroll
      for(int t=0;t<64;t++)
        p = fmaf(Av, p, bf2f(ub[XIDX(t, tid)]));
      P[(((b<<5)+c)<<10) + s] = p;
    }
  }
  // zero tail t-block (rows 2048..2063)
  if(c == 31){
    unsigned* zp = (unsigned*)(uB + (((size_t)b*129 + 128)*32)*512);
    for(int e = tid; e < 8192; e += 256) zp[e] = 0u;
  }
}

// ---- K3: boundary combine (inline) + pure in-place scan in h2 layout ----
__global__ __launch_bounds__(256) void k_h(unsigned short* __restrict__ uB,
    const float* __restrict__ A, const float* __restrict__ h0,
    const float* __restrict__ P){
  int wg = blockIdx.x;
  int half = wg & 1, c = (wg>>1) & 31, b = wg >> 6;
  int tid = threadIdx.x;
  int s = (half<<9) + (tid<<1);
  float2 Av = *(const float2*)(A + s);
  float a0 = Av.x, a1 = Av.y;
  #pragma unroll
  for(int sq=0;sq<6;sq++){ a0 *= a0; a1 *= a1; }   // A^64
  float2 hv = *(const float2*)(h0 + s);
  float h0v = hv.x, h1v = hv.y;
  const float2* Pb = (const float2*)(P + (((size_t)(b<<5))<<10) + s);
  for(int j=0;j<c;j++){
    float2 pv = Pb[(size_t)j<<9];
    h0v = fmaf(a0, h0v, pv.x);
    h1v = fmaf(a1, h1v, pv.y);
  }
  unsigned short* hb = uB + (((size_t)b*129 + c*4)*32 + (s>>5))*512 + (s&31);
  #pragma unroll 4
  for(int t=0;t<64;t++){
    unsigned* p = (unsigned*)(hb + ((t>>4)*32*512) + ((t&15)<<5));
    unsigned v = *p;
    h0v = fmaf(Av.x, h0v, bf2f((unsigned short)(v & 0xffff)));
    h1v = fmaf(Av.y, h1v, bf2f((unsigned short)(v >> 16)));
    *p = (unsigned)f2bf(h0v) | (((unsigned)f2bf(h1v))<<16);
  }
}

// ------- K4: AR-GEMM + C-GEMM, 2-deep prefetch pinned with sched_barrier ----
__global__ __launch_bounds__(256,2) void k_arc(const float* __restrict__ x,
    const unsigned short* __restrict__ Mt2, const unsigned short* __restrict__ Ct2,
    const unsigned short* __restrict__ h2, float* __restrict__ out){
  __shared__ __align__(16) unsigned short xt[73*256];
  int wg = blockIdx.x;
  int b = wg>>5, c = wg&31;
  int t0 = c*TCH;
  const float* xb = x + (size_t)b*SEQn*DIN;
  int tid = threadIdx.x;
  for(int e = tid; e < 73*64; e += 256){
    int r = e>>6, c4 = (e&63)<<2;
    int t = t0 - 9 + r;
    float4 v = {0.f,0.f,0.f,0.f};
    if(t >= 0) v = *(const float4*)(xb + t*DIN + c4);
    ushort4 w; w.x=f2bf(v.x); w.y=f2bf(v.y); w.z=f2bf(v.z); w.w=f2bf(v.w);
    *(ushort4*)&xt[XIDX(r, c4)] = w;
  }
  __syncthreads();
  int wv = tid>>6, ln = tid&63, lm = ln&15, lk = (ln>>4)<<3, rr = (ln>>4)<<2;
  f32x4 zf = {0.f,0.f,0.f,0.f};
  f32x4 acc[4][4];
  #pragma unroll
  for(int tt=0;tt<4;tt++)
    #pragma unroll
    for(int nt=0;nt<4;nt++) acc[tt][nt] = zf;

  // ---- AR GEMM: 80 K-iterations (it = i*8+kb8), groups of 2, pinned ping-pong
  const unsigned short* mb = Mt2 + ((((wv<<6)+lm)<<5) + lk);
  bf16x8 pA[8], pB[8];
#define LOADG(buf, IT0) { _Pragma("unroll") \
    for(int j=0;j<8;j++){ int itt=(IT0)+(j>>2); \
      buf[j] = *(const bf16x8*)&mb[((size_t)itt<<13) + ((j&3)<<9)]; } }
#define COMPG(buf, IT0) { _Pragma("unroll") \
    for(int jj=0;jj<2;jj++){ int itc=(IT0)+jj; int ii=itc>>3, k8=itc&7; \
      int col=(k8<<5)+lk; bf16x8 af[4]; \
      _Pragma("unroll") for(int tt=0;tt<4;tt++) \
        af[tt] = *(const bf16x8*)&xt[XIDX((tt<<4)+lm+9-ii, col)]; \
      _Pragma("unroll") for(int nt=0;nt<4;nt++){ \
        _Pragma("unroll") for(int tt=0;tt<4;tt++) \
          acc[tt][nt] = __builtin_amdgcn_mfma_f32_16x16x32_bf16(af[tt], buf[jj*4+nt], acc[tt][nt],0,0,0); } } }
  LOADG(pA, 0) SB;
  for(int g=0; g<80; g+=4){
    LOADG(pB, g+2) SB;
    COMPG(pA, g) SB;
    if(g+4 < 80) LOADG(pA, g+4)
    SB;
    COMPG(pB, g+2) SB;
  }

  // ---- C GEMM: 32 K-iterations, pinned prefetch of h2(af) + Ct2(bfr) ----
  const unsigned short* hb = h2 + (size_t)b*129*32*512;
  int Tg0 = c*4 + (lm>=6 ? 1 : 0);
  int rowin = (lm<6) ? (10+lm) : (lm-6);
  const unsigned short* hp[4];
  #pragma unroll
  for(int tt=0;tt<4;tt++)
    hp[tt] = hb + (((size_t)(Tg0+tt)*32)<<9) + rowin*32 + lk;
  const unsigned short* cb = Ct2 + ((((wv<<6)+lm)<<5) + lk);
  bf16x8 qa[4], qb4[4], qaf[4], qbf[4];
#define CLOADG(bufA, bufB, KB) { _Pragma("unroll") \
    for(int tt=0;tt<4;tt++) bufA[tt] = *(const bf16x8*)&hp[tt][((size_t)(KB))<<9]; \
    _Pragma("unroll") \
    for(int nt=0;nt<4;nt++) bufB[nt] = *(const bf16x8*)&cb[(((size_t)(KB))<<13) + (nt<<9)]; }
#define CCOMP(bufA, bufB) { _Pragma("unroll") \
    for(int nt=0;nt<4;nt++) \
      _Pragma("unroll") for(int tt=0;tt<4;tt++) \
        acc[tt][nt] = __builtin_amdgcn_mfma_f32_16x16x32_bf16(bufA[tt], bufB[nt], acc[tt][nt],0,0,0); }
  CLOADG(qaf, qbf, 0) SB;
  for(int kb=0; kb<32; kb+=2){
    CLOADG(qa, qb4, kb+1) SB;
    CCOMP(qaf, qbf) SB;
    if(kb+2 < 32) CLOADG(qaf, qbf, kb+2)
    SB;
    CCOMP(qa, qb4) SB;
  }

  #pragma unroll
  for(int tt=0;tt<4;tt++)
    #pragma unroll
    for(int nt=0;nt<4;nt++)
      #pragma unroll
      for(int r4=0;r4<4;r4++){
        int m = (tt<<4) + rr + r4;
        int o = (wv<<6) + (nt<<4) + lm;
        out[((size_t)b*SEQn + t0 + m)*DOUTn + o] = acc[tt][nt][r4];
      }
}

extern "C" void kernel_launch(void* const* d_in, const int* in_sizes, int n_in,
                              void* d_out, int out_size, void* d_ws, size_t ws_size,
                              hipStream_t stream){
  const float* x  = (const float*)d_in[0];
  const float* h0 = (const float*)d_in[1];
  const float* A  = (const float*)d_in[2];
  const float* C  = (const float*)d_in[4];
  const float* B  = (const float*)d_in[3];
  const float* M  = (const float*)d_in[5];
  float* out = (float*)d_out;
  unsigned short* Bt2 = (unsigned short*)d_ws;                   // 512 KB
  unsigned short* Ct2 = Bt2 + DIN*DST;                           // 512 KB
  unsigned short* Mt2 = Ct2 + DST*DOUTn;                         // 1.31 MB
  float* P     = (float*)((char*)d_ws + ( 4u<<20));              // 2 MB
  unsigned short* uB = (unsigned short*)((char*)d_ws + (8u<<20)); // 67.6 MB (uB/h2)
  k_prep <<<512, 256, 0, stream>>>(B, C, M, Bt2, Ct2, Mt2);
  k_ub   <<<BSZn*NCH, 256, 0, stream>>>(x, Bt2, A, uB, P);
  k_h    <<<BSZn*NCH*2, 256, 0, stream>>>(uB, A, h0, P);
  k_arc  <<<BSZn*NCH, 256, 0, stream>>>(x, Mt2, Ct2, uB, out);
}

// Round 9
// 250.358 us; speedup vs baseline: 1.1057x; 1.0064x over previous
//
#include <hip/hip_runtime.h>

#define BSZn 16
#define SEQn 2048
#define DIN 256
#define DST 1024
#define DOUTn 256
#define KXn 10
#define TCH 64
#define NCH 32

typedef __attribute__((ext_vector_type(4))) float f32x4;
typedef __attribute__((ext_vector_type(8))) short bf16x8;

__device__ __forceinline__ unsigned short f2bf(float f){
  unsigned u = __float_as_uint(f);
  u += 0x7FFF + ((u>>16)&1);
  return (unsigned short)(u>>16);
}
__device__ __forceinline__ float bf2f(unsigned short s){
  return __uint_as_float(((unsigned)s)<<16);
}
__device__ __forceinline__ void gl_lds16(const unsigned short* g, unsigned short* l){
  __builtin_amdgcn_global_load_lds(
      (const __attribute__((address_space(1))) void*)g,
      (__attribute__((address_space(3))) void*)l, 16, 0, 0);
}

// XOR-swizzled LDS element index for [*][256] bf16 tiles (row stride 512B)
#define XIDX(r,c) ((((r)<<8) + (c)) ^ (((r)&7)<<3))

// h2 fragment-major layout: element (t,s) of batch b lives at
//   ((b*129 + (t>>4))*32 + (s>>5))*512 + (t&15)*32 + (s&31)

// Weight slice layout (16KB = 8192 shorts per 32-wide K-slice):
//   element (n, kl) at  n*32 + ((kl>>3) ^ (n&3))*8 + (kl&7)
// swizzle pre-baked so global_load_lds copies LINEARLY; ds_read applies it.

// ------ K0: weight prep -> sliced fragment-major bf16 ------
__global__ void k_prep(const float* __restrict__ B, const float* __restrict__ C,
                       const float* __restrict__ M, unsigned short* __restrict__ Ut,
                       unsigned short* __restrict__ Wt){
  int stride = gridDim.x*blockDim.x;
  int i0 = blockIdx.x*blockDim.x + threadIdx.x;
  // B[d][s] -> Ut slice (q = s>>8, kb = d>>5)
  for(int idx=i0; idx<DIN*DST; idx+=stride){
    int d = idx>>10, s = idx&1023;
    int sl = s&255, kl = d&31;
    Ut[(size_t)(((s>>8)<<3)+(d>>5))*8192 + (sl<<5) + ((((kl>>3))^(sl&3))<<3) + (kl&7)]
      = f2bf(B[idx]);
  }
  // M[o][j][i] -> Wt slices 0..79  (k = i*256+j)
  for(int idx=i0; idx<DOUTn*DIN*KXn; idx+=stride){
    int q = idx/KXn, ii = idx - q*KXn;
    int o = q>>8, j = q&255;
    int kq = ii*8 + (j>>5), kl = j&31;
    Wt[(size_t)kq*8192 + (o<<5) + (((kl>>3)^(o&3))<<3) + (kl&7)] = f2bf(M[idx]);
  }
  // C[s][o] -> Wt slices 80..111 (k = s)
  for(int idx=i0; idx<DST*DOUTn; idx+=stride){
    int s = idx>>8, o = idx&255;
    int kq = 80 + (s>>5), kl = s&31;
    Wt[(size_t)kq*8192 + (o<<5) + (((kl>>3)^(o&3))<<3) + (kl&7)] = f2bf(C[idx]);
  }
}

// ---- K1: uB = x@B with 2-phase LDS-staged weights, h2-layout out + partials P
__global__ __launch_bounds__(256) void k_ub(const float* __restrict__ x,
    const unsigned short* __restrict__ Ut, const float* __restrict__ A,
    unsigned short* __restrict__ uB, float* __restrict__ P){
  __shared__ __align__(16) unsigned short xt[64*256];
  __shared__ __align__(16) unsigned short sh[2][8192];   // weight dbuf; reused as ub tile
  unsigned short* ubp = &sh[0][0];                       // [64][256] via XIDX
  int wg = blockIdx.x;
  int c = wg & 31, b = wg >> 5;
  int t0 = c*TCH;
  const float* xb = x + (size_t)b*SEQn*DIN;
  int tid = threadIdx.x;
  for(int e = tid; e < 64*64; e += 256){
    int r = e>>6, c4 = (e&63)<<2;
    float4 v = *(const float4*)(xb + (t0+r)*DIN + c4);
    ushort4 w; w.x=f2bf(v.x); w.y=f2bf(v.y); w.z=f2bf(v.z); w.w=f2bf(v.w);
    *(ushort4*)&xt[XIDX(r,c4)] = w;
  }
  int wv = tid>>6, ln = tid&63, lm = ln&15, lk = (ln>>4)<<3, rr = (ln>>4)<<2;
  int swz = ((ln>>4) ^ (lm&3)) << 3;
  unsigned short* hb = uB + ((size_t)b*129)*32*512;
  f32x4 zf = {0.f,0.f,0.f,0.f};
  for(int q=0;q<4;q++){
    int s0 = q<<8;
    __syncthreads();                       // xt staged / previous q's ub readers done
    { // prologue: stage slice (q,0)
      const unsigned short* src = Ut + (size_t)(q<<3)*8192;
      #pragma unroll
      for(int i=0;i<4;i++){ int ci=(i<<2)+wv; gl_lds16(src+ci*512+ln*8, &sh[0][ci*512]); }
    }
    __syncthreads();
    f32x4 acc[4][4];
    #pragma unroll
    for(int tt=0;tt<4;tt++)
      #pragma unroll
      for(int nt=0;nt<4;nt++) acc[tt][nt] = zf;
    int cur = 0;
    for(int kb=0;kb<8;kb++){
      if(kb<7){
        const unsigned short* src = Ut + (size_t)((q<<3)+kb+1)*8192;
        #pragma unroll
        for(int i=0;i<4;i++){ int ci=(i<<2)+wv; gl_lds16(src+ci*512+ln*8, &sh[cur^1][ci*512]); }
      }
      bf16x8 af[4], bfr[4];
      #pragma unroll
      for(int tt=0;tt<4;tt++)
        af[tt] = *(const bf16x8*)&xt[XIDX((tt<<4)+lm, (kb<<5)+lk)];
      #pragma unroll
      for(int nt=0;nt<4;nt++)
        bfr[nt] = *(const bf16x8*)&sh[cur][(((wv<<6)+(nt<<4)+lm)<<5) + swz];
      #pragma unroll
      for(int nt=0;nt<4;nt++)
        #pragma unroll
        for(int tt=0;tt<4;tt++)
          acc[tt][nt] = __builtin_amdgcn_mfma_f32_16x16x32_bf16(af[tt], bfr[nt], acc[tt][nt], 0,0,0);
      __syncthreads();
      cur ^= 1;
    }
    // acc -> ub tile (sh reused), then HBM h2-layout write + chunk partial
    #pragma unroll
    for(int tt=0;tt<4;tt++)
      #pragma unroll
      for(int nt=0;nt<4;nt++)
        #pragma unroll
        for(int r4=0;r4<4;r4++)
          ubp[XIDX((tt<<4)+rr+r4, (wv<<6)+(nt<<4)+lm)] = f2bf(acc[tt][nt][r4]);
    __syncthreads();
    #pragma unroll
    for(int it=0; it<8; it++){
      int j = it*256 + tid;
      int r = j>>5, c0 = (j&31)<<3;
      bf16x8 v = *(const bf16x8*)&ubp[XIDX(r,c0)];
      int s = s0 + c0;
      size_t addr = (((size_t)(c*4 + (r>>4)))*32 + (s>>5))*512 + ((r&15)<<5) + (s&31);
      *(bf16x8*)&hb[addr] = v;
    }
    {
      int s = s0 + tid;
      float Av = A[s];
      float p = 0.f;
      #pragma unroll
      for(int t=0;t<64;t++)
        p = fmaf(Av, p, bf2f(ubp[XIDX(t, tid)]));
      P[(((b<<5)+c)<<10) + s] = p;
    }
  }
  if(c == 31){
    unsigned* zp = (unsigned*)(uB + (((size_t)b*129 + 128)*32)*512);
    for(int e = tid; e < 8192; e += 256) zp[e] = 0u;
  }
}

// ---- K3: boundary combine (inline) + pure in-place scan in h2 layout ----
__global__ __launch_bounds__(256) void k_h(unsigned short* __restrict__ uB,
    const float* __restrict__ A, const float* __restrict__ h0,
    const float* __restrict__ P){
  int wg = blockIdx.x;
  int half = wg & 1, c = (wg>>1) & 31, b = wg >> 6;
  int tid = threadIdx.x;
  int s = (half<<9) + (tid<<1);
  float2 Av = *(const float2*)(A + s);
  float a0 = Av.x, a1 = Av.y;
  #pragma unroll
  for(int sq=0;sq<6;sq++){ a0 *= a0; a1 *= a1; }   // A^64
  float2 hv = *(const float2*)(h0 + s);
  float h0v = hv.x, h1v = hv.y;
  const float2* Pb = (const float2*)(P + (((size_t)(b<<5))<<10) + s);
  for(int j=0;j<c;j++){
    float2 pv = Pb[(size_t)j<<9];
    h0v = fmaf(a0, h0v, pv.x);
    h1v = fmaf(a1, h1v, pv.y);
  }
  unsigned short* hb = uB + (((size_t)b*129 + c*4)*32 + (s>>5))*512 + (s&31);
  #pragma unroll 4
  for(int t=0;t<64;t++){
    unsigned* p = (unsigned*)(hb + ((t>>4)*32*512) + ((t&15)<<5));
    unsigned v = *p;
    h0v = fmaf(Av.x, h0v, bf2f((unsigned short)(v & 0xffff)));
    h1v = fmaf(Av.y, h1v, bf2f((unsigned short)(v >> 16)));
    *p = (unsigned)f2bf(h0v) | (((unsigned)f2bf(h1v))<<16);
  }
}

// ------- K4: AR-GEMM + C-GEMM, 2-phase async LDS weight staging -------------
__global__ __launch_bounds__(256) void k_arc(const float* __restrict__ x,
    const unsigned short* __restrict__ Wt, const unsigned short* __restrict__ h2,
    float* __restrict__ out){
  __shared__ __align__(16) unsigned short xt[73*256];
  __shared__ __align__(16) unsigned short wb[2][8192];
  int wg = blockIdx.x;
  int b = wg>>5, c = wg&31;
  int t0 = c*TCH;
  const float* xb = x + (size_t)b*SEQn*DIN;
  int tid = threadIdx.x;
  int wv = tid>>6, ln = tid&63, lm = ln&15, lk = (ln>>4)<<3, rr = (ln>>4)<<2;
  int swz = ((ln>>4) ^ (lm&3)) << 3;
  for(int e = tid; e < 73*64; e += 256){
    int r = e>>6, c4 = (e&63)<<2;
    int t = t0 - 9 + r;
    float4 v = {0.f,0.f,0.f,0.f};
    if(t >= 0) v = *(const float4*)(xb + t*DIN + c4);
    ushort4 w; w.x=f2bf(v.x); w.y=f2bf(v.y); w.z=f2bf(v.z); w.w=f2bf(v.w);
    *(ushort4*)&xt[XIDX(r, c4)] = w;
  }
  { // prologue: stage slice 0
    #pragma unroll
    for(int i=0;i<4;i++){ int ci=(i<<2)+wv; gl_lds16(Wt+ci*512+ln*8, &wb[0][ci*512]); }
  }
  __syncthreads();
  f32x4 zf = {0.f,0.f,0.f,0.f};
  f32x4 acc[4][4];
  #pragma unroll
  for(int tt=0;tt<4;tt++)
    #pragma unroll
    for(int nt=0;nt<4;nt++) acc[tt][nt] = zf;
  int cur = 0;
  // ---- AR phases: kq = 0..79 ----
  for(int kq=0;kq<80;kq++){
    { // stage next slice (kq+1 <= 80 always valid)
      const unsigned short* src = Wt + (size_t)(kq+1)*8192;
      #pragma unroll
      for(int i=0;i<4;i++){ int ci=(i<<2)+wv; gl_lds16(src+ci*512+ln*8, &wb[cur^1][ci*512]); }
    }
    int ii = kq>>3, k8 = kq&7, col = (k8<<5)+lk;
    bf16x8 af[4], bfr[4];
    #pragma unroll
    for(int tt=0;tt<4;tt++)
      af[tt] = *(const bf16x8*)&xt[XIDX((tt<<4)+lm+9-ii, col)];
    #pragma unroll
    for(int nt=0;nt<4;nt++)
      bfr[nt] = *(const bf16x8*)&wb[cur][(((wv<<6)+(nt<<4)+lm)<<5) + swz];
    #pragma unroll
    for(int nt=0;nt<4;nt++)
      #pragma unroll
      for(int tt=0;tt<4;tt++)
        acc[tt][nt] = __builtin_amdgcn_mfma_f32_16x16x32_bf16(af[tt], bfr[nt], acc[tt][nt], 0,0,0);
    __syncthreads();
    cur ^= 1;
  }
  // ---- C phases: kb = 0..31, h fragments prefetched one phase ahead ----
  const unsigned short* hb = h2 + (size_t)b*129*32*512;
  int Tg0 = c*4 + (lm>=6 ? 1 : 0);
  int rowin = (lm<6) ? (10+lm) : (lm-6);
  const unsigned short* hp[4];
  #pragma unroll
  for(int tt=0;tt<4;tt++)
    hp[tt] = hb + (((size_t)(Tg0+tt)*32)<<9) + rowin*32 + lk;
  bf16x8 hEv[4], hOd[4];
  #pragma unroll
  for(int tt=0;tt<4;tt++) hEv[tt] = *(const bf16x8*)&hp[tt][0];
  for(int kb2=0; kb2<32; kb2+=2){
    // even phase kb2: stage slice 81+kb2, prefetch hOd(kb2+1), compute with hEv
    {
      const unsigned short* src = Wt + (size_t)(81+kb2)*8192;
      #pragma unroll
      for(int i=0;i<4;i++){ int ci=(i<<2)+wv; gl_lds16(src+ci*512+ln*8, &wb[cur^1][ci*512]); }
    }
    #pragma unroll
    for(int tt=0;tt<4;tt++) hOd[tt] = *(const bf16x8*)&hp[tt][(size_t)(kb2+1)<<9];
    {
      bf16x8 bfr[4];
      #pragma unroll
      for(int nt=0;nt<4;nt++)
        bfr[nt] = *(const bf16x8*)&wb[cur][(((wv<<6)+(nt<<4)+lm)<<5) + swz];
      #pragma unroll
      for(int nt=0;nt<4;nt++)
        #pragma unroll
        for(int tt=0;tt<4;tt++)
          acc[tt][nt] = __builtin_amdgcn_mfma_f32_16x16x32_bf16(hEv[tt], bfr[nt], acc[tt][nt], 0,0,0);
    }
    __syncthreads();
    cur ^= 1;
    // odd phase kb2+1: stage slice 82+kb2 (if exists), prefetch hEv(kb2+2), compute with hOd
    if(kb2+2 < 32){
      const unsigned short* src = Wt + (size_t)(82+kb2)*8192;
      #pragma unroll
      for(int i=0;i<4;i++){ int ci=(i<<2)+wv; gl_lds16(src+ci*512+ln*8, &wb[cur^1][ci*512]); }
      #pragma unroll
      for(int tt=0;tt<4;tt++) hEv[tt] = *(const bf16x8*)&hp[tt][(size_t)(kb2+2)<<9];
    }
    {
      bf16x8 bfr[4];
      #pragma unroll
      for(int nt=0;nt<4;nt++)
        bfr[nt] = *(const bf16x8*)&wb[cur][(((wv<<6)+(nt<<4)+lm)<<5) + swz];
      #pragma unroll
      for(int nt=0;nt<4;nt++)
        #pragma unroll
        for(int tt=0;tt<4;tt++)
          acc[tt][nt] = __builtin_amdgcn_mfma_f32_16x16x32_bf16(hOd[tt], bfr[nt], acc[tt][nt], 0,0,0);
    }
    __syncthreads();
    cur ^= 1;
  }
  #pragma unroll
  for(int tt=0;tt<4;tt++)
    #pragma unroll
    for(int nt=0;nt<4;nt++)
      #pragma unroll
      for(int r4=0;r4<4;r4++){
        int m = (tt<<4) + rr + r4;
        int o = (wv<<6) + (nt<<4) + lm;
        out[((size_t)b*SEQn + t0 + m)*DOUTn + o] = acc[tt][nt][r4];
      }
}

extern "C" void kernel_launch(void* const* d_in, const int* in_sizes, int n_in,
                              void* d_out, int out_size, void* d_ws, size_t ws_size,
                              hipStream_t stream){
  const float* x  = (const float*)d_in[0];
  const float* h0 = (const float*)d_in[1];
  const float* A  = (const float*)d_in[2];
  const float* B  = (const float*)d_in[3];
  const float* C  = (const float*)d_in[4];
  const float* M  = (const float*)d_in[5];
  float* out = (float*)d_out;
  unsigned short* Ut = (unsigned short*)d_ws;                     // 512 KB (32 slices)
  unsigned short* Wt = (unsigned short*)((char*)d_ws + (1u<<20)); // 1.83 MB (112 slices)
  float* P     = (float*)((char*)d_ws + (4u<<20));                // 2 MB
  unsigned short* uB = (unsigned short*)((char*)d_ws + (8u<<20)); // 67.6 MB (uB/h2)
  k_prep <<<512, 256, 0, stream>>>(B, C, M, Ut, Wt);
  k_ub   <<<BSZn*NCH, 256, 0, stream>>>(x, Ut, A, uB, P);
  k_h    <<<BSZn*NCH*2, 256, 0, stream>>>(uB, A, h0, P);
  k_arc  <<<BSZn*NCH, 256, 0, stream>>>(x, Wt, uB, out);
}